// Round 4
// baseline (2053.940 us; speedup 1.0000x reference)
//
#include <hip/hip_runtime.h>
#include <stdint.h>
#include <stddef.h>

#define NBATCH 32
#define HW     16384      // 128*128
#define CCH    128

typedef short bf16x8 __attribute__((ext_vector_type(8)));
typedef float f32x4  __attribute__((ext_vector_type(4)));

__device__ __forceinline__ float bf2f(unsigned short u){
    union { unsigned int i; float f; } v; v.i = ((unsigned int)u) << 16; return v.f;
}
__device__ __forceinline__ unsigned short f2bf(float f){
    union { float f; unsigned int i; } v; v.f = f;
    unsigned int x = v.i;
    x += 0x7fffu + ((x >> 16) & 1u);   // round-to-nearest-even
    return (unsigned short)(x >> 16);
}
// extract halfword j (0..3) of a uint2 holding 4 bf16 (hw-consecutive)
__device__ __forceinline__ unsigned int h16(uint2 u, int j){
    unsigned int v = (j & 2) ? u.y : u.x;
    return (j & 1) ? (v >> 16) : (v & 0xffffu);
}

// ---------------------------------------------------------------- weight prep (hi/lo split):
// layout per conv: [NCH][2][M][32] bf16, half0=hi, half1=lo, K zero/dup-padded.
//   Wab1 @0       [1][2][256][32]
//   Wc1  @16384   [5][2][128][32]
//   Wab2 @57344   [4][2][256][32]
//   Wc2  @122880  [8][2][128][32]
//   Wab3 @188416  [4][2][256][32]
//   Wc3  @253952  [8][2][128][32]   total 319488 shorts
#define WPREP_TOTAL 319488
__global__ __launch_bounds__(256) void k_prep(
    const float* __restrict__ w11, const float* __restrict__ w12, const float* __restrict__ w13,
    const float* __restrict__ w21, const float* __restrict__ w22, const float* __restrict__ w23,
    const float* __restrict__ w31, const float* __restrict__ w32, const float* __restrict__ w33,
    unsigned short* __restrict__ wp)
{
    int i = blockIdx.x*256 + threadIdx.x;
    if(i >= WPREP_TOTAL) return;
    float v; int half;
    if(i < 16384){
        int j = i; half = (j >> 13) & 1;
        int r = (j >> 5) & 255, c = j & 31, col = c & 15;
        v = (r < 128) ? w11[r*16 + col] : w12[(r-128)*16 + col];
    } else if(i < 57344){
        int j = i - 16384; int ck = j >> 13; int jj = j & 8191;
        half = jj >> 12;
        int r = (jj >> 5) & 127, c = jj & 31;
        int col = (ck < 4) ? (ck*32 + c) : (128 + (c & 15));
        v = w13[r*144 + col];
    } else if(i < 122880){
        int j = i - 57344; int ck = j >> 14; int jj = j & 16383;
        half = jj >> 13;
        int r = (jj >> 5) & 255, c = jj & 31, col = ck*32 + c;
        v = (r < 128) ? w21[r*128 + col] : w22[(r-128)*128 + col];
    } else if(i < 188416){
        int j = i - 122880; int ck = j >> 13; int jj = j & 8191;
        half = jj >> 12;
        int r = (jj >> 5) & 127, c = jj & 31, col = ck*32 + c;
        v = w23[r*256 + col];
    } else if(i < 253952){
        int j = i - 188416; int ck = j >> 14; int jj = j & 16383;
        half = jj >> 13;
        int r = (jj >> 5) & 255, c = jj & 31, col = ck*32 + c;
        v = (r < 128) ? w31[r*128 + col] : w32[(r-128)*128 + col];
    } else {
        int j = i - 253952; int ck = j >> 13; int jj = j & 8191;
        half = jj >> 12;
        int r = (jj >> 5) & 127, c = jj & 31, col = ck*32 + c;
        v = w33[r*256 + col];
    }
    unsigned short hi = f2bf(v);
    wp[i] = half ? f2bf(v - bf2f(hi)) : hi;
}

// ---------------------------------------------------------------- X2 hi/lo split
__global__ __launch_bounds__(256) void k_xprep(const float* __restrict__ X2, unsigned short* __restrict__ X2b){
    int i = blockIdx.x*256 + threadIdx.x;        // over 32*16*HW
    int hw = i & (HW-1);
    int rest = i >> 14;
    int c = rest & 15, b = rest >> 4;
    float v = X2[i];
    unsigned short hi = f2bf(v);
    size_t dst = (size_t)b*32*HW + (size_t)c*HW + hw;
    X2b[dst] = hi;
    X2b[dst + (size_t)16*HW] = f2bf(v - bf2f(hi));
}

// ---------------------------------------------------------------- Msum = M[:,0]+M[:,1]
__global__ __launch_bounds__(256) void k_msum(const float* __restrict__ M, float* __restrict__ msum){
    int i = blockIdx.x*256 + threadIdx.x;
    int b = i >> 14, hw = i & (HW-1);
    msum[i] = M[(size_t)b*2*HW + hw] + M[(size_t)b*2*HW + HW + hw];
}

// ---------------------------------------------------------------- fused conv a+b (MFMA GEMM, split-W, pipelined)
// Out[256][hw]: rows<128 -> A, rows>=128 -> B. M=256, Ntile=128, KC=32 x 2 MFMA.
template<int NCH, int CIN, bool GX>
__global__ __launch_bounds__(256,2) void k_cab(
    const unsigned short* __restrict__ Wp,   // [NCH][2][256][32] bf16
    const unsigned short* __restrict__ xin,  // bf16 [b][CIN][HW]
    const float* __restrict__ ba, const float* __restrict__ bb,
    const float* __restrict__ msum,
    unsigned short* __restrict__ A, unsigned short* __restrict__ Bm, int b0)
{
    __shared__ unsigned short Wl[16384];     // [2][256][32] unpadded (bank-uniform for frag reads)
    __shared__ unsigned short Xt[128*40];    // [hw][ch] stride 40
    const int bi = blockIdx.y, bg = b0 + bi;
    const int hw0 = blockIdx.x * 128;
    const int t = threadIdx.x;
    const int w = t >> 6, l = t & 63;
    const int lr = l & 15, lg = l >> 4;
    const int cg8 = t & 7;                   // ch = cg8*4 + i
    const int h4  = t >> 3;                  // hw = h4*4 + j
    const unsigned short* xbase = xin + (size_t)(GX ? bg : bi)*CIN*HW;

    f32x4 acc[4][8];
    #pragma unroll
    for(int mf=0; mf<4; mf++)
        #pragma unroll
        for(int nf=0; nf<8; nf++) acc[mf][nf] = (f32x4){0.f,0.f,0.f,0.f};

    uint4 w0r[8], w1r[8];
    uint2 x0r[4], x1r[4];

    auto loadW = [&](int ck, uint4 (&wr)[8]){
        const unsigned short* src = Wp + (size_t)ck*16384 + (size_t)t*8;
        #pragma unroll
        for(int r=0;r<8;r++) wr[r] = *reinterpret_cast<const uint4*>(src + (size_t)r*2048);
    };
    auto writeW = [&](uint4 (&wr)[8]){
        #pragma unroll
        for(int r=0;r<8;r++) *reinterpret_cast<uint4*>(&Wl[(r*256+t)*8]) = wr[r];
    };
    auto loadX = [&](int ck, uint2 (&xr)[4]){
        const unsigned short* p = xbase + (size_t)(ck*32)*HW + hw0 + h4*4;
        #pragma unroll
        for(int i=0;i<4;i++) xr[i] = *reinterpret_cast<const uint2*>(p + (size_t)(cg8*4+i)*HW);
    };
    auto writeX = [&](uint2 (&xr)[4]){
        #pragma unroll
        for(int j=0;j<4;j++){
            uint2 pk;
            pk.x = h16(xr[0],j) | (h16(xr[1],j) << 16);
            pk.y = h16(xr[2],j) | (h16(xr[3],j) << 16);
            *reinterpret_cast<uint2*>(&Xt[(h4*4+j)*40 + cg8*4]) = pk;
        }
    };
    auto compute = [&](){
        bf16x8 ah[4], al[4];
        #pragma unroll
        for(int mf=0; mf<4; mf++){
            ah[mf] = *reinterpret_cast<const bf16x8*>(&Wl[(w*64 + mf*16 + lr)*32 + lg*8]);
            al[mf] = *reinterpret_cast<const bf16x8*>(&Wl[8192 + (w*64 + mf*16 + lr)*32 + lg*8]);
        }
        #pragma unroll
        for(int nf=0; nf<8; nf++){
            bf16x8 bfr = *reinterpret_cast<const bf16x8*>(&Xt[(nf*16 + lr)*40 + lg*8]);
            #pragma unroll
            for(int mf=0; mf<4; mf++){
                acc[mf][nf] = __builtin_amdgcn_mfma_f32_16x16x32_bf16(ah[mf], bfr, acc[mf][nf], 0,0,0);
                acc[mf][nf] = __builtin_amdgcn_mfma_f32_16x16x32_bf16(al[mf], bfr, acc[mf][nf], 0,0,0);
            }
        }
    };
    auto step = [&](int ck, uint4(&wc)[8], uint2(&xc)[4], uint4(&wn)[8], uint2(&xn)[4]){
        writeW(wc); writeX(xc);
        __syncthreads();
        if(ck+1 < NCH){ loadW(ck+1, wn); loadX(ck+1, xn); }   // in flight under compute
        compute();
        __syncthreads();
    };

    loadW(0, w0r); loadX(0, x0r);
    for(int ck=0; ck<NCH; ck+=2){
        step(ck, w0r, x0r, w1r, x1r);
        if(ck+1 < NCH) step(ck+1, w1r, x1r, w0r, x0r);
    }

    // ---- epilogue: bias, *Msum, relu, bf16 store
    float msv[8];
    #pragma unroll
    for(int nf=0; nf<8; nf++) msv[nf] = msum[(size_t)bg*HW + hw0 + nf*16 + lr];
    const float* bsel = (w < 2) ? ba : bb;
    unsigned short* dst = ((w < 2) ? A : Bm) + (size_t)bi*CCH*HW;
    const int rbase = (w & 1) * 64;
    #pragma unroll
    for(int mf=0; mf<4; mf++){
        #pragma unroll
        for(int reg=0; reg<4; reg++){
            int rl = rbase + mf*16 + lg*4 + reg;
            float bv = bsel[rl];
            #pragma unroll
            for(int nf=0; nf<8; nf++){
                float v2 = (acc[mf][nf][reg] + bv) * msv[nf];
                v2 = v2 > 0.f ? v2 : 0.f;
                dst[(size_t)rl*HW + hw0 + nf*16 + lr] = f2bf(v2);
            }
        }
    }
}

// ---------------------------------------------------------------- conv c (concat GEMM, split-W, pipelined) + fused diag-reduce
// Out[128][hw] = relu((wc [P;x] + bc)ms); xo += sum(out*Mdiag). M=128, Ntile=256.
template<int NCHP, int NCHX, int CINX, bool GX>
__global__ __launch_bounds__(256,2) void k_cc(
    const unsigned short* __restrict__ Wp,   // [NCHP+NCHX][2][128][32] bf16
    const unsigned short* __restrict__ P,    // bf16 [bi][128][HW]
    const unsigned short* __restrict__ x2,   // bf16 [b][CINX][HW]
    const float* __restrict__ bc,
    const float* __restrict__ msum, const float* __restrict__ M,
    unsigned short* __restrict__ Xout, float* __restrict__ xo,
    int b0, int xo_off)
{
    constexpr int NCH = NCHP + NCHX;
    __shared__ unsigned short Wl[8192];      // [2][128][32] unpadded
    __shared__ unsigned short Xt[256*40];    // [hw][ch] stride 40
    const int bi = blockIdx.y, bg = b0 + bi;
    const int hw0 = blockIdx.x * 256;
    const int t = threadIdx.x;
    const int w = t >> 6, l = t & 63;
    const int lr = l & 15, lg = l >> 4;
    const int cg = t & 3;                    // ch = cg*8 + i
    const int h4 = t >> 2;                   // hw = h4*4 + j  (0..63)
    const unsigned short* pbase = P  + (size_t)bi*CCH*HW;
    const unsigned short* xbase = x2 + (size_t)(GX ? bg : bi)*CINX*HW;

    f32x4 acc[8][4];
    #pragma unroll
    for(int mf=0; mf<8; mf++)
        #pragma unroll
        for(int nf=0; nf<4; nf++) acc[mf][nf] = (f32x4){0.f,0.f,0.f,0.f};

    uint4 w0r[4], w1r[4];
    uint2 x0r[8], x1r[8];

    auto loadW = [&](int ck, uint4 (&wr)[4]){
        const unsigned short* src = Wp + (size_t)ck*8192 + (size_t)t*8;
        #pragma unroll
        for(int r=0;r<4;r++) wr[r] = *reinterpret_cast<const uint4*>(src + (size_t)r*2048);
    };
    auto writeW = [&](uint4 (&wr)[4]){
        #pragma unroll
        for(int r=0;r<4;r++) *reinterpret_cast<uint4*>(&Wl[(r*256+t)*8]) = wr[r];
    };
    auto loadX = [&](int ck, uint2 (&xr)[8]){
        const unsigned short* xs = (ck < NCHP)
            ? (pbase + (size_t)(ck*32)*HW)
            : (xbase + (size_t)((ck-NCHP)*32)*HW);
        const unsigned short* p = xs + hw0 + h4*4;
        #pragma unroll
        for(int i=0;i<8;i++) xr[i] = *reinterpret_cast<const uint2*>(p + (size_t)(cg*8+i)*HW);
    };
    auto writeX = [&](uint2 (&xr)[8]){
        #pragma unroll
        for(int j=0;j<4;j++){
            uint4 pk;
            pk.x = h16(xr[0],j) | (h16(xr[1],j) << 16);
            pk.y = h16(xr[2],j) | (h16(xr[3],j) << 16);
            pk.z = h16(xr[4],j) | (h16(xr[5],j) << 16);
            pk.w = h16(xr[6],j) | (h16(xr[7],j) << 16);
            *reinterpret_cast<uint4*>(&Xt[(h4*4+j)*40 + cg*8]) = pk;
        }
    };
    auto compute = [&](){
        bf16x8 bfr[4];
        #pragma unroll
        for(int nf=0; nf<4; nf++)
            bfr[nf] = *reinterpret_cast<const bf16x8*>(&Xt[(w*64 + nf*16 + lr)*40 + lg*8]);
        #pragma unroll
        for(int mf=0; mf<8; mf++){
            bf16x8 ah = *reinterpret_cast<const bf16x8*>(&Wl[(mf*16 + lr)*32 + lg*8]);
            bf16x8 al = *reinterpret_cast<const bf16x8*>(&Wl[4096 + (mf*16 + lr)*32 + lg*8]);
            #pragma unroll
            for(int nf=0; nf<4; nf++){
                acc[mf][nf] = __builtin_amdgcn_mfma_f32_16x16x32_bf16(ah, bfr[nf], acc[mf][nf], 0,0,0);
                acc[mf][nf] = __builtin_amdgcn_mfma_f32_16x16x32_bf16(al, bfr[nf], acc[mf][nf], 0,0,0);
            }
        }
    };
    auto step = [&](int ck, uint4(&wc)[4], uint2(&xc)[8], uint4(&wn)[4], uint2(&xn)[8]){
        writeW(wc); writeX(xc);
        __syncthreads();
        if(ck+1 < NCH){ loadW(ck+1, wn); loadX(ck+1, xn); }
        compute();
        __syncthreads();
    };

    loadW(0, w0r); loadX(0, x0r);
    for(int ck=0; ck<NCH; ck+=2){
        step(ck, w0r, x0r, w1r, x1r);
        if(ck+1 < NCH) step(ck+1, w1r, x1r, w0r, x0r);
    }

    // ---- epilogue: bias, *Msum, relu, store; fused xo += sum(out * Mdiag)
    float msv[4], mdv[4];
    #pragma unroll
    for(int nf=0; nf<4; nf++){
        int hwi = hw0 + w*64 + nf*16 + lr;
        msv[nf] = msum[(size_t)bg*HW + hwi];
        mdv[nf] = M[(size_t)bg*2*HW + hwi];
    }
    unsigned short* dst = Xout + (size_t)bi*CCH*HW;
    #pragma unroll
    for(int mf=0; mf<8; mf++){
        float red[4] = {0.f,0.f,0.f,0.f};
        #pragma unroll
        for(int reg=0; reg<4; reg++){
            int row = mf*16 + lg*4 + reg;
            float bv = bc[row];
            #pragma unroll
            for(int nf=0; nf<4; nf++){
                float v2 = (acc[mf][nf][reg] + bv) * msv[nf];
                v2 = v2 > 0.f ? v2 : 0.f;
                dst[(size_t)row*HW + hw0 + w*64 + nf*16 + lr] = f2bf(v2);
                red[reg] += v2 * mdv[nf];
            }
        }
        #pragma unroll
        for(int reg=0; reg<4; reg++){
            float r = red[reg];
            r += __shfl_xor(r, 1);
            r += __shfl_xor(r, 2);
            r += __shfl_xor(r, 4);
            r += __shfl_xor(r, 8);
            if(lr == 0)
                atomicAdd(&xo[(size_t)bg*384 + xo_off + mf*16 + lg*4 + reg], r);
        }
    }
}

// ---------------------------------------------------------------- batched spatial matmul:
// P[b,c] = (A[b,c] @ B[b,c]) * Msum[b]   (128x128x128, bf16 MFMA, fp32 accum)
__global__ __launch_bounds__(256) void k_bmm(
    const unsigned short* __restrict__ A, const unsigned short* __restrict__ Bm,
    const float* __restrict__ msum, unsigned short* __restrict__ P, int b0)
{
    __shared__ unsigned short Bs[128*136];
    const int m  = blockIdx.x;
    const int bi = m >> 7;
    const int bg = b0 + bi;
    const unsigned short* Ab = A  + (size_t)m*HW;
    const unsigned short* Bb = Bm + (size_t)m*HW;
    unsigned short*       Pb = P  + (size_t)m*HW;
    const float* ms = msum + (size_t)bg*HW;
    const int t = threadIdx.x;
    const int w  = t >> 6;
    const int l  = t & 63;
    const int lr = l & 15;
    const int lg = l >> 4;

    // hoist all A-fragment loads (direct global) -- in flight during B staging
    bf16x8 af[4][2];
    #pragma unroll
    for(int kk=0;kk<4;kk++)
        #pragma unroll
        for(int rt=0;rt<2;rt++)
            af[kk][rt] = *reinterpret_cast<const bf16x8*>(Ab + (size_t)(w*32 + rt*16 + lr)*128 + kk*32 + lg*8);

    // stage B transposed: Bs[j][k] = B[k][j]
    #pragma unroll
    for(int it=0; it<8; it++){
        int task = it*256 + t;
        int j  = task & 127;
        int kg = task >> 7;
        unsigned short v[8];
        #pragma unroll
        for(int i=0;i<8;i++) v[i] = Bb[(size_t)(kg*8+i)*128 + j];
        uint4 pk;
        pk.x = (unsigned int)v[0] | ((unsigned int)v[1]<<16);
        pk.y = (unsigned int)v[2] | ((unsigned int)v[3]<<16);
        pk.z = (unsigned int)v[4] | ((unsigned int)v[5]<<16);
        pk.w = (unsigned int)v[6] | ((unsigned int)v[7]<<16);
        *reinterpret_cast<uint4*>(&Bs[j*136 + kg*8]) = pk;
    }
    __syncthreads();

    f32x4 acc[2][8];
    #pragma unroll
    for(int rt=0;rt<2;rt++)
        #pragma unroll
        for(int ct=0;ct<8;ct++) acc[rt][ct] = (f32x4){0.f,0.f,0.f,0.f};

    #pragma unroll
    for(int kk=0;kk<4;kk++){
        #pragma unroll
        for(int ct=0;ct<8;ct++){
            bf16x8 bfr = *reinterpret_cast<const bf16x8*>(&Bs[(ct*16+lr)*136 + kk*32 + lg*8]);
            acc[0][ct] = __builtin_amdgcn_mfma_f32_16x16x32_bf16(af[kk][0], bfr, acc[0][ct], 0,0,0);
            acc[1][ct] = __builtin_amdgcn_mfma_f32_16x16x32_bf16(af[kk][1], bfr, acc[1][ct], 0,0,0);
        }
    }
    #pragma unroll
    for(int rt=0;rt<2;rt++){
        #pragma unroll
        for(int ct=0;ct<8;ct++){
            #pragma unroll
            for(int r=0;r<4;r++){
                int row = w*32 + rt*16 + lg*4 + r;
                int col = ct*16 + lr;
                float v = acc[rt][ct][r] * ms[row*128 + col];
                Pb[(size_t)row*128 + col] = f2bf(v);
            }
        }
    }
}

// ---------------------------------------------------------------- head
__global__ __launch_bounds__(1024) void k_head(
    const float* __restrict__ xo, const float* __restrict__ h1w, const float* __restrict__ h1b,
    const float* __restrict__ h2w, const float* __restrict__ h2b, float* __restrict__ out)
{
    __shared__ float hbuf[NBATCH][32];
    const int t = threadIdx.x;
    const int b = t >> 5, j = t & 31;
    float a = h1b[j];
    #pragma unroll 8
    for(int k=0;k<384;k++) a += xo[b*384+k]*h1w[j*384+k];
    a = a > 0.f ? a : 0.f;
    hbuf[b][j] = a;
    __syncthreads();
    if(j == 0){
        float s = h2b[0];
        #pragma unroll
        for(int k=0;k<32;k++) s += hbuf[b][k]*h2w[k];
        out[b] = s;
    }
}

// ----------------------------------------------------------------
extern "C" void kernel_launch(void* const* d_in, const int* in_sizes, int n_in,
                              void* d_out, int out_size, void* d_ws, size_t ws_size,
                              hipStream_t stream)
{
    (void)in_sizes; (void)n_in; (void)out_size;
    const float* X2  = (const float*)d_in[0];
    const float* M   = (const float*)d_in[1];
    const float* w11 = (const float*)d_in[2];  const float* b11 = (const float*)d_in[3];
    const float* w12 = (const float*)d_in[4];  const float* b12 = (const float*)d_in[5];
    const float* w13 = (const float*)d_in[6];  const float* b13 = (const float*)d_in[7];
    const float* w21 = (const float*)d_in[8];  const float* b21 = (const float*)d_in[9];
    const float* w22 = (const float*)d_in[10]; const float* b22 = (const float*)d_in[11];
    const float* w23 = (const float*)d_in[12]; const float* b23 = (const float*)d_in[13];
    const float* w31 = (const float*)d_in[14]; const float* b31 = (const float*)d_in[15];
    const float* w32 = (const float*)d_in[16]; const float* b32 = (const float*)d_in[17];
    const float* w33 = (const float*)d_in[18]; const float* b33 = (const float*)d_in[19];
    const float* h1w = (const float*)d_in[20]; const float* h1b = (const float*)d_in[21];
    const float* h2w = (const float*)d_in[22]; const float* h2b = (const float*)d_in[23];
    float* out = (float*)d_out;

    char* ws = (char*)d_ws;
    size_t off = 0;
    float* msum = (float*)(ws + off); off += (size_t)NBATCH*HW*4;            // 2 MB
    float* xo   = (float*)(ws + off); off += (size_t)NBATCH*384*4;           // 48 KB
    unsigned short* wp  = (unsigned short*)(ws + off); off += (size_t)WPREP_TOTAL*2;
    off = (off + 255) & ~(size_t)255;
    unsigned short* X2b = (unsigned short*)(ws + off); off += (size_t)NBATCH*32*HW*2;  // 33.5 MB
    off = (off + 255) & ~(size_t)255;

    int bc = 32;
    while (bc > 1 && off + 4ull*(size_t)bc*CCH*HW*2 > ws_size) bc >>= 1;
    size_t bufb = (size_t)bc*CCH*HW*2;
    unsigned short* bufA = (unsigned short*)(ws + off);
    unsigned short* bufB = (unsigned short*)(ws + off + bufb);
    unsigned short* bufP = (unsigned short*)(ws + off + 2*bufb);
    unsigned short* bufX = (unsigned short*)(ws + off + 3*bufb);

    const unsigned short* Wab1 = wp + 0;
    const unsigned short* Wc1  = wp + 16384;
    const unsigned short* Wab2 = wp + 57344;
    const unsigned short* Wc2  = wp + 122880;
    const unsigned short* Wab3 = wp + 188416;
    const unsigned short* Wc3  = wp + 253952;

    k_prep<<<(WPREP_TOTAL+255)/256, 256, 0, stream>>>(w11,w12,w13,w21,w22,w23,w31,w32,w33, wp);
    k_xprep<<<(NBATCH*16*HW)/256, 256, 0, stream>>>(X2, X2b);
    k_msum<<<(NBATCH*HW)/256, 256, 0, stream>>>(M, msum);
    hipMemsetAsync(xo, 0, (size_t)NBATCH*384*4, stream);

    for(int b0 = 0; b0 < NBATCH; b0 += bc){
        dim3 gab(HW/128, bc);
        dim3 gcc(HW/256, bc);
        dim3 gmat(bc*CCH);
        // ---- block 1
        k_cab<1,32,true  ><<<gab, 256, 0, stream>>>(Wab1, X2b,  b11, b12, msum, bufA, bufB, b0);
        k_bmm<<<gmat, 256, 0, stream>>>(bufA, bufB, msum, bufP, b0);
        k_cc <4,1,32,true ><<<gcc, 256, 0, stream>>>(Wc1, bufP, X2b,  b13, msum, M, bufX, xo, b0, 0);
        // ---- block 2
        k_cab<4,128,false><<<gab, 256, 0, stream>>>(Wab2, bufX, b21, b22, msum, bufA, bufB, b0);
        k_bmm<<<gmat, 256, 0, stream>>>(bufA, bufB, msum, bufP, b0);
        k_cc <4,4,128,false><<<gcc, 256, 0, stream>>>(Wc2, bufP, bufX, b23, msum, M, bufA, xo, b0, 128);
        // ---- block 3
        k_cab<4,128,false><<<gab, 256, 0, stream>>>(Wab3, bufA, b31, b32, msum, bufB, bufP, b0);
        k_bmm<<<gmat, 256, 0, stream>>>(bufB, bufP, msum, bufX, b0);
        k_cc <4,4,128,false><<<gcc, 256, 0, stream>>>(Wc3, bufX, bufA, b33, msum, M, bufB, xo, b0, 256);
    }
    k_head<<<1, 1024, 0, stream>>>(xo, h1w, h1b, h2w, h2b, out);
}

// Round 5
// 1174.147 us; speedup vs baseline: 1.7493x; 1.7493x over previous
//
#include <hip/hip_runtime.h>
#include <stdint.h>
#include <stddef.h>

#define NBATCH 32
#define HW     16384      // 128*128
#define CCH    128
#define WROW   40         // padded W row stride (shorts), 5x16B per row
#define WCHUNK 10240      // [2][128][40] shorts per K-chunk (20 KB)

typedef short bf16x8 __attribute__((ext_vector_type(8)));
typedef float f32x4  __attribute__((ext_vector_type(4)));

__device__ __forceinline__ float bf2f(unsigned short u){
    union { unsigned int i; float f; } v; v.i = ((unsigned int)u) << 16; return v.f;
}
__device__ __forceinline__ unsigned short f2bf(float f){
    union { float f; unsigned int i; } v; v.f = f;
    unsigned int x = v.i;
    x += 0x7fffu + ((x >> 16) & 1u);   // round-to-nearest-even
    return (unsigned short)(x >> 16);
}
__device__ __forceinline__ unsigned int h16(uint2 u, int j){
    unsigned int v = (j & 2) ? u.y : u.x;
    return (j & 1) ? (v >> 16) : (v & 0xffffu);
}
// global -> LDS async DMA, 16B per lane (CK-style addrspace casts)
__device__ __forceinline__ void gl_lds16(const unsigned short* g, unsigned short* l){
    __builtin_amdgcn_global_load_lds(
        reinterpret_cast<const __attribute__((address_space(1))) unsigned int*>(
            reinterpret_cast<uintptr_t>(g)),
        reinterpret_cast<__attribute__((address_space(3))) unsigned int*>(
            reinterpret_cast<uintptr_t>(l)),
        16, 0, 0);
}

// ---------------------------------------------------------------- weight prep:
// per conv: [NCH][2][128][40] bf16 (half0=hi, half1=lo), cols 32..39 zero pad.
// segments (shorts): wa1@0, wb1@10240, wc1@20480(n5), wa2@71680(n4), wb2@112640,
// wc2@153600(n8), wa3@235520, wb3@276480, wc3@317440(n8). total 399360.
#define WPREP_TOTAL 399360
__global__ __launch_bounds__(256) void k_prep(
    const float* __restrict__ w11, const float* __restrict__ w12, const float* __restrict__ w13,
    const float* __restrict__ w21, const float* __restrict__ w22, const float* __restrict__ w23,
    const float* __restrict__ w31, const float* __restrict__ w32, const float* __restrict__ w33,
    unsigned short* __restrict__ wp)
{
    int i = blockIdx.x*256 + threadIdx.x;
    if(i >= WPREP_TOTAL) return;
    const float* src; int K, mode, base;
    if     (i < 10240) { src=w11; K=16;  mode=1; base=0;      }
    else if(i < 20480) { src=w12; K=16;  mode=1; base=10240;  }
    else if(i < 71680) { src=w13; K=144; mode=2; base=20480;  }
    else if(i < 112640){ src=w21; K=128; mode=0; base=71680;  }
    else if(i < 153600){ src=w22; K=128; mode=0; base=112640; }
    else if(i < 235520){ src=w23; K=256; mode=0; base=153600; }
    else if(i < 276480){ src=w31; K=128; mode=0; base=235520; }
    else if(i < 317440){ src=w32; K=128; mode=0; base=276480; }
    else               { src=w33; K=256; mode=0; base=317440; }
    int j  = i - base;
    int ck = j / WCHUNK;
    int jj = j - ck*WCHUNK;
    int half = jj / 5120;
    int rr   = (jj / WROW) & 127;
    int c    = jj % WROW;
    float v = 0.f;
    if(c < 32){
        int col = (mode==1) ? (c & 15)
                : (mode==2) ? (ck < 4 ? ck*32 + c : 128 + (c & 15))
                :             ck*32 + c;
        v = src[rr*K + col];
    }
    unsigned short hi = f2bf(v);
    wp[i] = half ? f2bf(v - bf2f(hi)) : hi;
}

// ---------------------------------------------------------------- Msum = M[:,0]+M[:,1]
__global__ __launch_bounds__(256) void k_msum(const float* __restrict__ M, float* __restrict__ msum){
    int i = blockIdx.x*256 + threadIdx.x;
    int b = i >> 14, hw = i & (HW-1);
    msum[i] = M[(size_t)b*2*HW + hw] + M[(size_t)b*2*HW + HW + hw];
}

// ---------------------------------------------------------------- unified conv GEMM
// Out[128][hw-tile 256] = relu((W @ concat(P, X) + bias) * Msum); M=128, KC=32 (x2 hi/lo MFMA).
// CC: fused diag-reduce into xo. !CC: grid.z picks (wa->OutA)/(wb->OutB).
// XS: X-part read from fp32 X2 with in-kernel hi/lo split (NCHX must be 1).
template<int NCHP, int NCHX, bool CC, bool XS>
__global__ __launch_bounds__(256,2) void k_conv(
    const unsigned short* __restrict__ Wp,
    const unsigned short* __restrict__ Psrc,
    const void* __restrict__ Xsrc,
    const float* __restrict__ biasA, const float* __restrict__ biasB,
    const float* __restrict__ msum, const float* __restrict__ Mfull,
    unsigned short* __restrict__ OutA, unsigned short* __restrict__ OutB,
    float* __restrict__ xo, int b0, int xo_off)
{
    constexpr int NCH = NCHP + NCHX;
    __shared__ unsigned short Wl[2*WCHUNK];      // double-buffered W, 40 KB
    __shared__ unsigned short Xt[256*WROW];      // X^T tile, 20 KB
    const int bi = blockIdx.y, bg = b0 + bi;
    const int hw0 = blockIdx.x * 256;
    const int z = CC ? 0 : blockIdx.z;
    const int t = threadIdx.x;
    const int w = t >> 6, l = t & 63;
    const int lr = l & 15, lg = l >> 4;
    const int wm = w & 1, wn = w >> 1;           // 2x2 wave grid: rows 64*wm, cols 128*wn
    const int cg = t & 3, h4 = t >> 2;           // X staging mapping
    const unsigned short* Wseg  = Wp + (size_t)z*NCH*WCHUNK;
    const unsigned short* pbase = (NCHP > 0) ? (Psrc + (size_t)bi*CCH*HW) : nullptr;
    const float* xfbase = nullptr;
    const unsigned short* xbbase = nullptr;
    if constexpr (XS) xfbase = (const float*)Xsrc + (size_t)bg*16*HW;
    else              xbbase = (const unsigned short*)Xsrc + (size_t)bi*CCH*HW;

    f32x4 acc[4][8];
    #pragma unroll
    for(int mf=0; mf<4; mf++)
        #pragma unroll
        for(int nf=0; nf<8; nf++) acc[mf][nf] = (f32x4){0.f,0.f,0.f,0.f};

    uint2 xr0[8], xr1[8];
    float xf0[16], xf1[16];

    auto wdma = [&](int ck){
        const unsigned short* src = Wseg + (size_t)ck*WCHUNK + (size_t)t*8;
        unsigned short* dstl = &Wl[(ck & 1)*WCHUNK + t*8];
        #pragma unroll
        for(int r=0; r<5; r++)
            gl_lds16(src + (size_t)r*2048, dstl + r*2048);
    };
    auto loadXb = [&](int ck, uint2 (&xr)[8]){
        const unsigned short* s = ((ck < NCHP) ? (pbase + (size_t)ck*32*HW)
                                               : (xbbase + (size_t)(ck-NCHP)*32*HW))
                                  + hw0 + h4*4;
        #pragma unroll
        for(int i=0;i<8;i++) xr[i] = *reinterpret_cast<const uint2*>(s + (size_t)(cg*8+i)*HW);
    };
    auto loadXf = [&](float (&xf)[16]){
        const float* s = xfbase + hw0 + t;
        #pragma unroll
        for(int c=0;c<16;c++) xf[c] = s[(size_t)c*HW];
    };
    auto writeXb = [&](uint2 (&xr)[8]){
        #pragma unroll
        for(int j=0;j<4;j++){
            uint4 pk;
            pk.x = h16(xr[0],j) | (h16(xr[1],j) << 16);
            pk.y = h16(xr[2],j) | (h16(xr[3],j) << 16);
            pk.z = h16(xr[4],j) | (h16(xr[5],j) << 16);
            pk.w = h16(xr[6],j) | (h16(xr[7],j) << 16);
            *reinterpret_cast<uint4*>(&Xt[(h4*4+j)*WROW + cg*8]) = pk;
        }
    };
    auto writeXf = [&](float (&xf)[16]){
        unsigned int hi[16], lo[16];
        #pragma unroll
        for(int c=0;c<16;c++){
            unsigned short h = f2bf(xf[c]);
            hi[c] = h;
            lo[c] = f2bf(xf[c] - bf2f(h));
        }
        uint4 a, b2, c4, d;
        a.x  = hi[0] |(hi[1] <<16); a.y  = hi[2] |(hi[3] <<16); a.z  = hi[4] |(hi[5] <<16); a.w  = hi[6] |(hi[7] <<16);
        b2.x = hi[8] |(hi[9] <<16); b2.y = hi[10]|(hi[11]<<16); b2.z = hi[12]|(hi[13]<<16); b2.w = hi[14]|(hi[15]<<16);
        c4.x = lo[0] |(lo[1] <<16); c4.y = lo[2] |(lo[3] <<16); c4.z = lo[4] |(lo[5] <<16); c4.w = lo[6] |(lo[7] <<16);
        d.x  = lo[8] |(lo[9] <<16); d.y  = lo[10]|(lo[11]<<16); d.z  = lo[12]|(lo[13]<<16); d.w  = lo[14]|(lo[15]<<16);
        unsigned short* base = &Xt[t*WROW];
        *reinterpret_cast<uint4*>(base +  0) = a;
        *reinterpret_cast<uint4*>(base +  8) = b2;
        *reinterpret_cast<uint4*>(base + 16) = c4;
        *reinterpret_cast<uint4*>(base + 24) = d;
    };
    auto do_load = [&](int ck, uint2 (&xr)[8], float (&xf)[16]){
        if(ck < NCHP) loadXb(ck, xr);
        else if constexpr (XS) loadXf(xf);
        else loadXb(ck, xr);
    };
    auto do_write = [&](int ck, uint2 (&xr)[8], float (&xf)[16]){
        if(ck < NCHP) writeXb(xr);
        else if constexpr (XS) writeXf(xf);
        else writeXb(xr);
    };
    auto compute = [&](int ck){
        const unsigned short* Wb = &Wl[(ck & 1)*WCHUNK];
        bf16x8 ah[4], al[4];
        #pragma unroll
        for(int mf=0; mf<4; mf++){
            ah[mf] = *reinterpret_cast<const bf16x8*>(&Wb[(wm*64 + mf*16 + lr)*WROW + lg*8]);
            al[mf] = *reinterpret_cast<const bf16x8*>(&Wb[(128 + wm*64 + mf*16 + lr)*WROW + lg*8]);
        }
        #pragma unroll
        for(int nf=0; nf<8; nf++){
            bf16x8 bfr = *reinterpret_cast<const bf16x8*>(&Xt[(wn*128 + nf*16 + lr)*WROW + lg*8]);
            #pragma unroll
            for(int mf=0; mf<4; mf++){
                acc[mf][nf] = __builtin_amdgcn_mfma_f32_16x16x32_bf16(ah[mf], bfr, acc[mf][nf], 0,0,0);
                acc[mf][nf] = __builtin_amdgcn_mfma_f32_16x16x32_bf16(al[mf], bfr, acc[mf][nf], 0,0,0);
            }
        }
    };

    // prologue: chunk 0 in flight
    wdma(0);
    do_load(0, xr0, xf0);

    #pragma unroll
    for(int ck=0; ck<NCH; ck+=2){
        // even chunk: consume set0, prefetch set1
        do_write(ck, xr0, xf0);                               // waits its own loads
        asm volatile("s_waitcnt vmcnt(0) lgkmcnt(0)" ::: "memory");
        __builtin_amdgcn_s_barrier();
        if(ck+1 < NCH){ wdma(ck+1); do_load(ck+1, xr1, xf1); }  // fly under compute
        compute(ck);
        __builtin_amdgcn_s_barrier();                          // no vmcnt: prefetch stays in flight
        if(ck+1 < NCH){
            // odd chunk: consume set1, prefetch set0
            do_write(ck+1, xr1, xf1);
            asm volatile("s_waitcnt vmcnt(0) lgkmcnt(0)" ::: "memory");
            __builtin_amdgcn_s_barrier();
            if(ck+2 < NCH){ wdma(ck+2); do_load(ck+2, xr0, xf0); }
            compute(ck+1);
            __builtin_amdgcn_s_barrier();
        }
    }

    // ---- epilogue: bias, *Msum, relu, store (+ fused diag reduce for CC)
    float msv[8], mdv[8];
    #pragma unroll
    for(int nf=0; nf<8; nf++){
        int hwi = hw0 + wn*128 + nf*16 + lr;
        msv[nf] = msum[(size_t)bg*HW + hwi];
        if constexpr (CC) mdv[nf] = Mfull[(size_t)bg*2*HW + hwi];
    }
    const float* bias = z ? biasB : biasA;
    unsigned short* dst = (z ? OutB : OutA) + (size_t)bi*CCH*HW;
    #pragma unroll
    for(int mf=0; mf<4; mf++){
        float red[4] = {0.f,0.f,0.f,0.f};
        #pragma unroll
        for(int reg=0; reg<4; reg++){
            int row = wm*64 + mf*16 + lg*4 + reg;
            float bv = bias[row];
            #pragma unroll
            for(int nf=0; nf<8; nf++){
                float v2 = (acc[mf][nf][reg] + bv) * msv[nf];
                v2 = v2 > 0.f ? v2 : 0.f;
                dst[(size_t)row*HW + hw0 + wn*128 + nf*16 + lr] = f2bf(v2);
                if constexpr (CC) red[reg] += v2 * mdv[nf];
            }
        }
        if constexpr (CC){
            #pragma unroll
            for(int reg=0; reg<4; reg++){
                float r = red[reg];
                r += __shfl_xor(r, 1);
                r += __shfl_xor(r, 2);
                r += __shfl_xor(r, 4);
                r += __shfl_xor(r, 8);
                if(lr == 0)
                    atomicAdd(&xo[(size_t)bg*384 + xo_off + wm*64 + mf*16 + lg*4 + reg], r);
            }
        }
    }
}

// ---------------------------------------------------------------- batched spatial matmul:
// P[b,c] = (A[b,c] @ B[b,c]) * Msum[b]  (128x128x128 bf16 MFMA; P may alias A)
__global__ __launch_bounds__(256) void k_bmm(
    const unsigned short* __restrict__ A, const unsigned short* __restrict__ Bm,
    const float* __restrict__ msum, unsigned short* __restrict__ P, int b0)
{
    __shared__ unsigned short Bs[128*136];
    const int m  = blockIdx.x;
    const int bi = m >> 7;
    const int bg = b0 + bi;
    const unsigned short* Ab = A  + (size_t)m*HW;
    const unsigned short* Bb = Bm + (size_t)m*HW;
    unsigned short*       Pb = P  + (size_t)m*HW;
    const float* ms = msum + (size_t)bg*HW;
    const int t = threadIdx.x;
    const int w  = t >> 6;
    const int l  = t & 63;
    const int lr = l & 15;
    const int lg = l >> 4;

    // hoist all A-fragment loads; in flight during B staging
    bf16x8 af[4][2];
    #pragma unroll
    for(int kk=0;kk<4;kk++)
        #pragma unroll
        for(int rt=0;rt<2;rt++)
            af[kk][rt] = *reinterpret_cast<const bf16x8*>(Ab + (size_t)(w*32 + rt*16 + lr)*128 + kk*32 + lg*8);

    #pragma unroll
    for(int it=0; it<8; it++){
        int task = it*256 + t;
        int j  = task & 127;
        int kg = task >> 7;
        unsigned short v[8];
        #pragma unroll
        for(int i=0;i<8;i++) v[i] = Bb[(size_t)(kg*8+i)*128 + j];
        uint4 pk;
        pk.x = (unsigned int)v[0] | ((unsigned int)v[1]<<16);
        pk.y = (unsigned int)v[2] | ((unsigned int)v[3]<<16);
        pk.z = (unsigned int)v[4] | ((unsigned int)v[5]<<16);
        pk.w = (unsigned int)v[6] | ((unsigned int)v[7]<<16);
        *reinterpret_cast<uint4*>(&Bs[j*136 + kg*8]) = pk;
    }
    __syncthreads();

    f32x4 acc[2][8];
    #pragma unroll
    for(int rt=0;rt<2;rt++)
        #pragma unroll
        for(int ct=0;ct<8;ct++) acc[rt][ct] = (f32x4){0.f,0.f,0.f,0.f};

    #pragma unroll
    for(int kk=0;kk<4;kk++){
        #pragma unroll
        for(int ct=0;ct<8;ct++){
            bf16x8 bfr = *reinterpret_cast<const bf16x8*>(&Bs[(ct*16+lr)*136 + kk*32 + lg*8]);
            acc[0][ct] = __builtin_amdgcn_mfma_f32_16x16x32_bf16(af[kk][0], bfr, acc[0][ct], 0,0,0);
            acc[1][ct] = __builtin_amdgcn_mfma_f32_16x16x32_bf16(af[kk][1], bfr, acc[1][ct], 0,0,0);
        }
    }
    #pragma unroll
    for(int rt=0;rt<2;rt++){
        #pragma unroll
        for(int ct=0;ct<8;ct++){
            #pragma unroll
            for(int r=0;r<4;r++){
                int row = w*32 + rt*16 + lg*4 + r;
                int col = ct*16 + lr;
                float v = acc[rt][ct][r] * ms[row*128 + col];
                Pb[(size_t)row*128 + col] = f2bf(v);
            }
        }
    }
}

// ---------------------------------------------------------------- head
__global__ __launch_bounds__(1024) void k_head(
    const float* __restrict__ xo, const float* __restrict__ h1w, const float* __restrict__ h1b,
    const float* __restrict__ h2w, const float* __restrict__ h2b, float* __restrict__ out)
{
    __shared__ float hbuf[NBATCH][32];
    const int t = threadIdx.x;
    const int b = t >> 5, j = t & 31;
    float a = h1b[j];
    #pragma unroll 8
    for(int k=0;k<384;k++) a += xo[b*384+k]*h1w[j*384+k];
    a = a > 0.f ? a : 0.f;
    hbuf[b][j] = a;
    __syncthreads();
    if(j == 0){
        float s = h2b[0];
        #pragma unroll
        for(int k=0;k<32;k++) s += hbuf[b][k]*h2w[k];
        out[b] = s;
    }
}

// ----------------------------------------------------------------
extern "C" void kernel_launch(void* const* d_in, const int* in_sizes, int n_in,
                              void* d_out, int out_size, void* d_ws, size_t ws_size,
                              hipStream_t stream)
{
    (void)in_sizes; (void)n_in; (void)out_size;
    const float* X2  = (const float*)d_in[0];
    const float* M   = (const float*)d_in[1];
    const float* w11 = (const float*)d_in[2];  const float* b11 = (const float*)d_in[3];
    const float* w12 = (const float*)d_in[4];  const float* b12 = (const float*)d_in[5];
    const float* w13 = (const float*)d_in[6];  const float* b13 = (const float*)d_in[7];
    const float* w21 = (const float*)d_in[8];  const float* b21 = (const float*)d_in[9];
    const float* w22 = (const float*)d_in[10]; const float* b22 = (const float*)d_in[11];
    const float* w23 = (const float*)d_in[12]; const float* b23 = (const float*)d_in[13];
    const float* w31 = (const float*)d_in[14]; const float* b31 = (const float*)d_in[15];
    const float* w32 = (const float*)d_in[16]; const float* b32 = (const float*)d_in[17];
    const float* w33 = (const float*)d_in[18]; const float* b33 = (const float*)d_in[19];
    const float* h1w = (const float*)d_in[20]; const float* h1b = (const float*)d_in[21];
    const float* h2w = (const float*)d_in[22]; const float* h2b = (const float*)d_in[23];
    float* out = (float*)d_out;

    char* ws = (char*)d_ws;
    size_t off = 0;
    float* msum = (float*)(ws + off); off += (size_t)NBATCH*HW*4;            // 2 MB
    float* xo   = (float*)(ws + off); off += (size_t)NBATCH*384*4;           // 48 KB
    unsigned short* wp = (unsigned short*)(ws + off); off += (size_t)WPREP_TOTAL*2;  // 780 KB
    off = (off + 255) & ~(size_t)255;

    int bc = 32;
    while (bc > 1 && off + 3ull*(size_t)bc*CCH*HW*2 > ws_size) bc >>= 1;
    size_t bufb = (size_t)bc*CCH*HW*2;
    unsigned short* buf0 = (unsigned short*)(ws + off);
    unsigned short* buf1 = (unsigned short*)(ws + off + bufb);
    unsigned short* buf2 = (unsigned short*)(ws + off + 2*bufb);

    const unsigned short* Wa1 = wp + 0;        // z=1 -> +10240 = wb1
    const unsigned short* Wc1 = wp + 20480;
    const unsigned short* Wa2 = wp + 71680;    // z=1 -> +40960 = wb2
    const unsigned short* Wc2 = wp + 153600;
    const unsigned short* Wa3 = wp + 235520;   // z=1 -> +40960 = wb3
    const unsigned short* Wc3 = wp + 317440;

    k_prep<<<(WPREP_TOTAL+255)/256, 256, 0, stream>>>(w11,w12,w13,w21,w22,w23,w31,w32,w33, wp);
    k_msum<<<(NBATCH*HW)/256, 256, 0, stream>>>(M, msum);
    hipMemsetAsync(xo, 0, (size_t)NBATCH*384*4, stream);

    for(int b0 = 0; b0 < NBATCH; b0 += bc){
        dim3 gab(HW/256, bc, 2);
        dim3 gcc(HW/256, bc);
        dim3 gmat(bc*CCH);
        // ---- block 1 (X from fp32 X2, in-kernel hi/lo split)
        k_conv<0,1,false,true ><<<gab, 256, 0, stream>>>(Wa1, nullptr, X2, b11, b12, msum, M, buf0, buf1, nullptr, b0, 0);
        k_bmm<<<gmat, 256, 0, stream>>>(buf0, buf1, msum, buf0, b0);
        k_conv<4,1,true ,true ><<<gcc, 256, 0, stream>>>(Wc1, buf0, X2, b13, b13, msum, M, buf1, nullptr, xo, b0, 0);
        // ---- block 2 (X = buf1)
        k_conv<0,4,false,false><<<gab, 256, 0, stream>>>(Wa2, nullptr, buf1, b21, b22, msum, M, buf2, buf0, nullptr, b0, 0);
        k_bmm<<<gmat, 256, 0, stream>>>(buf2, buf0, msum, buf2, b0);
        k_conv<4,4,true ,false><<<gcc, 256, 0, stream>>>(Wc2, buf2, buf1, b23, b23, msum, M, buf0, nullptr, xo, b0, 128);
        // ---- block 3 (X = buf0)
        k_conv<0,4,false,false><<<gab, 256, 0, stream>>>(Wa3, nullptr, buf0, b31, b32, msum, M, buf1, buf2, nullptr, b0, 0);
        k_bmm<<<gmat, 256, 0, stream>>>(buf1, buf2, msum, buf1, b0);
        k_conv<4,4,true ,false><<<gcc, 256, 0, stream>>>(Wc3, buf1, buf0, b33, b33, msum, M, buf2, nullptr, xo, b0, 256);
    }
    k_head<<<1, 1024, 0, stream>>>(xo, h1w, h1b, h2w, h2b, out);
}